// Round 13
// baseline (666.300 us; speedup 1.0000x reference)
//
#include <hip/hip_runtime.h>
#include <hip/hip_cooperative_groups.h>

namespace cg = cooperative_groups;

#define TILE_SHIFT 5   // 32x32-px tiles
#define NXCD 8

// R12 journal: quad-staged LDS gather REGRESSED (117.8 vs 105 us): ds_read
// latency ~120cy !<< banded-L2 ~150-200cy, LDS 63KB halved occupancy, staging
// +17MB FETCH. Reverted to R11 iterate; this round fuses the 6-dispatch
// pre-pass into one cooperative kernel (126us of launch+serial-scan overhead).

__device__ __forceinline__ int point_tile_rm(const int* inds, int n, int N,
                                             int H, int W, int tiles_x)
{
    int y = inds[n];
    int x = inds[N + n];
    int ty = min(max(y, 0), H - 1) >> TILE_SHIFT;
    int tx = min(max(x, 0), W - 1) >> TILE_SHIFT;
    return ty * tiles_x + tx;
}

// ---------------------------------------------------------------------------
// Fused cooperative kernel: interleave | zero | hist | scan | scatter | iterate
// Gated on: N == gridDim*256, gridDim % 8 == 0, (HW/4) % gridDim == 0.
// ---------------------------------------------------------------------------
__global__ __launch_bounds__(256) void fused_kernel(
    const float* __restrict__ dP, float2* __restrict__ im,
    int* __restrict__ perm, int* __restrict__ hist, int* __restrict__ cursor,
    const int* __restrict__ inds, const int* __restrict__ niter_p,
    float* __restrict__ out, int H, int W, int N, int HW)
{
#pragma clang fp contract(off)
    cg::grid_group grid = cg::this_grid();
    const int tid  = threadIdx.x;
    const int bid  = blockIdx.x;
    const int nblk = gridDim.x;
    const int gtid = bid * 256 + tid;
    const int gsize = nblk * 256;

    // XCD-banded block id: XCD k (bid%8) owns contiguous chunk k
    const int cpx  = nblk >> 3;
    const int sbid = (bid & (NXCD - 1)) * cpx + (bid >> 3);

    const float sH = (float)(H - 1);
    const float sW = (float)(W - 1);
    const float s0 = 2.0f / sH;        // im ch0 scale (= dP[1])
    const float s1 = 2.0f / sW;        // im ch1 scale (= dP[0])
    const int tiles_x = ((W - 1) >> TILE_SHIFT) + 1;
    const int tiles_y = ((H - 1) >> TILE_SHIFT) + 1;
    const int ntiles  = tiles_x * tiles_y;

    // ---- P0: interleave (contiguous rows per swizzled block) -------------
    {
        const int nquad   = HW >> 2;
        const int per_blk = nquad / nblk;          // exact (host gate)
        const int base    = sbid * per_blk;
        const float4* p0 = reinterpret_cast<const float4*>(dP);       // dP[0]
        const float4* p1 = reinterpret_cast<const float4*>(dP + HW);  // dP[1]
        float4* outv = reinterpret_cast<float4*>(im);
        for (int j = tid; j < per_blk; j += 256) {
            int i = base + j;
            float4 a = p1[i];
            float4 b = p0[i];
            float4 lo, hi;
            lo.x = a.x * s0; lo.y = b.x * s1; lo.z = a.y * s0; lo.w = b.y * s1;
            hi.x = a.z * s0; hi.y = b.z * s1; hi.z = a.w * s0; hi.w = b.w * s1;
            outv[2 * i]     = lo;
            outv[2 * i + 1] = hi;
        }
    }
    // ---- P1: zero hist (overlaps P0 stores; ordered by grid.sync) --------
    for (int i = gtid; i < ntiles; i += gsize) hist[i] = 0;
    grid.sync();

    // ---- P2: histogram ----------------------------------------------------
    if (gtid < N)
        atomicAdd(&hist[point_tile_rm(inds, gtid, N, H, W, tiles_x)], 1);
    grid.sync();

    // ---- P3: exclusive scan (block 0; 1023 blocks idle ~us at the sync) ---
    if (bid == 0) {
        __shared__ int partial[256];
        const int items = (ntiles + 255) >> 8;
        const int basei = tid * items;
        int sum = 0;
        for (int i = 0; i < items; ++i) {
            int idx = basei + i;
            if (idx < ntiles) sum += hist[idx];
        }
        partial[tid] = sum;
        __syncthreads();
        for (int off = 1; off < 256; off <<= 1) {
            int v = (tid >= off) ? partial[tid - off] : 0;
            __syncthreads();
            partial[tid] += v;
            __syncthreads();
        }
        int excl = (tid == 0) ? 0 : partial[tid - 1];
        for (int i = 0; i < items; ++i) {
            int idx = basei + i;
            if (idx < ntiles) {
                int h = hist[idx];
                cursor[idx] = excl;
                excl += h;
            }
        }
    }
    grid.sync();

    // ---- P4: scatter -> perm ----------------------------------------------
    if (gtid < N) {
        int slot = atomicAdd(&cursor[point_tile_rm(inds, gtid, N, H, W, tiles_x)], 1);
        perm[slot] = gtid;
    }
    grid.sync();

    // ---- P5: iterate (R11-verified math, 1 pt/thread, banded chunk) -------
    {
        const int t = sbid * 256 + tid;
        if (t < N) {
            const int pid = perm[t];
            const int niter = niter_p[0];
            const float Wf = (float)W, Hf = (float)H;

            float px = ((float)inds[N + pid] / sH) * 2.0f - 1.0f;
            float py = ((float)inds[pid]     / sW) * 2.0f - 1.0f;

            for (int it = 0; it < niter; ++it) {
                float x = ((px + 1.0f) * Wf - 1.0f) * 0.5f;
                float y = ((py + 1.0f) * Hf - 1.0f) * 0.5f;
                float x0f = floorf(x), y0f = floorf(y);
                float wx1 = x - x0f,  wy1 = y - y0f;
                float wx0 = 1.0f - wx1, wy0 = 1.0f - wy1;
                int x0 = (int)x0f, y0 = (int)y0f;
                int x1 = x0 + 1,   y1 = y0 + 1;

                int x0c = min(max(x0, 0), W - 1);
                int x1c = min(max(x1, 0), W - 1);
                int y0c = min(max(y0, 0), H - 1);
                int y1c = min(max(y1, 0), H - 1);
                bool bx0 = (x0 >= 0) & (x0 < W);
                bool bx1 = (x1 >= 0) & (x1 < W);
                bool by0 = (y0 >= 0) & (y0 < H);
                bool by1 = (y1 >= 0) & (y1 < H);

                const float2* r0 = im + (size_t)y0c * W;
                const float2* r1 = im + (size_t)y1c * W;
                float2 v00 = r0[x0c], v10 = r0[x1c];
                float2 v01 = r1[x0c], v11 = r1[x1c];

                const float2 zero = make_float2(0.0f, 0.0f);
                if (!(bx0 & by0)) v00 = zero;
                if (!(bx1 & by0)) v10 = zero;
                if (!(bx0 & by1)) v01 = zero;
                if (!(bx1 & by1)) v11 = zero;

                float w00 = wx0 * wy0, w10 = wx1 * wy0;
                float w01 = wx0 * wy1, w11 = wx1 * wy1;
                float dx = ((v00.x * w00 + v10.x * w10) + v01.x * w01) + v11.x * w11;
                float dy = ((v00.y * w00 + v10.y * w10) + v01.y * w01) + v11.y * w11;

                px = fminf(fmaxf(px + dx, -1.0f), 1.0f);
                py = fminf(fmaxf(py + dy, -1.0f), 1.0f);
            }

            out[pid]     = (py + 1.0f) * 0.5f * sW;
            out[N + pid] = (px + 1.0f) * 0.5f * sH;
        }
    }
}

// ===========================================================================
// Fallback path: exact R11-verified multi-launch pipeline.
// ===========================================================================
__global__ __launch_bounds__(256) void interleave_kernel(
    const float* __restrict__ dP, float2* __restrict__ im,
    int HW, float s0, float s1, int swz_on)
{
    int bid = blockIdx.x;
    if (swz_on) {
        int cpx = gridDim.x >> 3;
        bid = (bid & (NXCD - 1)) * cpx + (bid >> 3);
    }
    int i = bid * blockDim.x + threadIdx.x;
    int nquad = HW >> 2;
    if (i >= nquad) return;
    const float4* p0 = reinterpret_cast<const float4*>(dP);
    const float4* p1 = reinterpret_cast<const float4*>(dP + HW);
    float4 a = p1[i];
    float4 b = p0[i];
    float4 lo, hi;
    lo.x = a.x * s0; lo.y = b.x * s1; lo.z = a.y * s0; lo.w = b.y * s1;
    hi.x = a.z * s0; hi.y = b.z * s1; hi.z = a.w * s0; hi.w = b.w * s1;
    float4* outv = reinterpret_cast<float4*>(im);
    outv[2 * i]     = lo;
    outv[2 * i + 1] = hi;
}

__global__ __launch_bounds__(256) void zero_kernel(int* __restrict__ p, int n)
{
    int i = blockIdx.x * blockDim.x + threadIdx.x;
    if (i < n) p[i] = 0;
}

__global__ __launch_bounds__(256) void hist_kernel(
    const int* __restrict__ inds, int* __restrict__ hist,
    int N, int H, int W, int tiles_x)
{
    int n = blockIdx.x * blockDim.x + threadIdx.x;
    if (n >= N) return;
    atomicAdd(&hist[point_tile_rm(inds, n, N, H, W, tiles_x)], 1);
}

__global__ __launch_bounds__(1024) void scan_kernel(
    const int* __restrict__ hist, int* __restrict__ cursor, int ntiles)
{
    __shared__ int partial[1024];
    const int tid = threadIdx.x;
    const int items = (ntiles + 1023) >> 10;
    const int base = tid * items;
    int sum = 0;
    for (int i = 0; i < items; ++i) {
        int idx = base + i;
        if (idx < ntiles) sum += hist[idx];
    }
    partial[tid] = sum;
    __syncthreads();
    for (int off = 1; off < 1024; off <<= 1) {
        int v = (tid >= off) ? partial[tid - off] : 0;
        __syncthreads();
        partial[tid] += v;
        __syncthreads();
    }
    int excl = (tid == 0) ? 0 : partial[tid - 1];
    for (int i = 0; i < items; ++i) {
        int idx = base + i;
        if (idx < ntiles) {
            int h = hist[idx];
            cursor[idx] = excl;
            excl += h;
        }
    }
}

__global__ __launch_bounds__(256) void scatter_kernel(
    const int* __restrict__ inds, int* __restrict__ cursor,
    int* __restrict__ perm, int N, int H, int W, int tiles_x)
{
    int n = blockIdx.x * blockDim.x + threadIdx.x;
    if (n >= N) return;
    int slot = atomicAdd(&cursor[point_tile_rm(inds, n, N, H, W, tiles_x)], 1);
    perm[slot] = n;
}

template <int MODE>
__global__ __launch_bounds__(256) void iterate1_kernel(
    const float2* __restrict__ im, const float* __restrict__ dP,
    const int* __restrict__ perm,
    const int* __restrict__ inds, const int* __restrict__ niter_p,
    float* __restrict__ out, int H, int W, int N, int swz_on)
{
#pragma clang fp contract(off)
    int bid = blockIdx.x;
    if (swz_on) {
        int cpx = gridDim.x >> 3;
        bid = (bid & (NXCD - 1)) * cpx + (bid >> 3);
    }
    const int t = bid * blockDim.x + threadIdx.x;
    if (t >= N) return;
    const int niter = niter_p[0];
    const float sH = (float)(H - 1);
    const float sW = (float)(W - 1);
    const float s0 = 2.0f / sH;
    const float s1 = 2.0f / sW;
    const int HW = H * W;
    const float Wf = (float)W, Hf = (float)H;

    const int pid = (MODE == 2) ? perm[t] : t;

    float px = ((float)inds[N + pid] / sH) * 2.0f - 1.0f;
    float py = ((float)inds[pid]     / sW) * 2.0f - 1.0f;

    for (int it = 0; it < niter; ++it) {
        float x = ((px + 1.0f) * Wf - 1.0f) * 0.5f;
        float y = ((py + 1.0f) * Hf - 1.0f) * 0.5f;
        float x0f = floorf(x), y0f = floorf(y);
        float wx1 = x - x0f,  wy1 = y - y0f;
        float wx0 = 1.0f - wx1, wy0 = 1.0f - wy1;
        int x0 = (int)x0f, y0 = (int)y0f;
        int x1 = x0 + 1,   y1 = y0 + 1;

        int x0c = min(max(x0, 0), W - 1);
        int x1c = min(max(x1, 0), W - 1);
        int y0c = min(max(y0, 0), H - 1);
        int y1c = min(max(y1, 0), H - 1);
        bool bx0 = (x0 >= 0) & (x0 < W);
        bool bx1 = (x1 >= 0) & (x1 < W);
        bool by0 = (y0 >= 0) & (y0 < H);
        bool by1 = (y1 >= 0) & (y1 < H);

        float2 v00, v10, v01, v11;
        if (MODE >= 1) {
            const float2* r0 = im + (size_t)y0c * W;
            const float2* r1 = im + (size_t)y1c * W;
            v00 = r0[x0c]; v10 = r0[x1c];
            v01 = r1[x0c]; v11 = r1[x1c];
        } else {
            int i00 = y0c * W + x0c, i10 = y0c * W + x1c;
            int i01 = y1c * W + x0c, i11 = y1c * W + x1c;
            v00 = make_float2(dP[HW + i00] * s0, dP[i00] * s1);
            v10 = make_float2(dP[HW + i10] * s0, dP[i10] * s1);
            v01 = make_float2(dP[HW + i01] * s0, dP[i01] * s1);
            v11 = make_float2(dP[HW + i11] * s0, dP[i11] * s1);
        }
        const float2 zero = make_float2(0.0f, 0.0f);
        if (!(bx0 & by0)) v00 = zero;
        if (!(bx1 & by0)) v10 = zero;
        if (!(bx0 & by1)) v01 = zero;
        if (!(bx1 & by1)) v11 = zero;

        float w00 = wx0 * wy0, w10 = wx1 * wy0;
        float w01 = wx0 * wy1, w11 = wx1 * wy1;
        float dx = ((v00.x * w00 + v10.x * w10) + v01.x * w01) + v11.x * w11;
        float dy = ((v00.y * w00 + v10.y * w10) + v01.y * w01) + v11.y * w11;

        px = fminf(fmaxf(px + dx, -1.0f), 1.0f);
        py = fminf(fmaxf(py + dy, -1.0f), 1.0f);
    }

    out[pid]     = (py + 1.0f) * 0.5f * sW;
    out[N + pid] = (px + 1.0f) * 0.5f * sH;
}

extern "C" void kernel_launch(void* const* d_in, const int* in_sizes, int n_in,
                              void* d_out, int out_size, void* d_ws, size_t ws_size,
                              hipStream_t stream) {
    const float* dP      = (const float*)d_in[0];
    const int*   inds    = (const int*)d_in[1];
    const int*   niter_p = (const int*)d_in[2];
    float*       out     = (float*)d_out;

    const int HW = in_sizes[0] / 2;
    int W = 1;
    while ((long long)W * W < (long long)HW) W <<= 1;  // 4194304 -> 2048
    const int H = HW / W;
    const int N = in_sizes[1] / 2;

    const float s0 = 2.0f / (float)(H - 1);
    const float s1 = 2.0f / (float)(W - 1);

    const int tiles_x = ((W - 1) >> TILE_SHIFT) + 1;
    const int tiles_y = ((H - 1) >> TILE_SHIFT) + 1;
    const int ntiles  = tiles_x * tiles_y;

    const size_t im_bytes   = (size_t)HW * sizeof(float2);
    const size_t perm_bytes = (size_t)N * sizeof(int);
    const size_t aux_bytes  = (size_t)2 * ntiles * sizeof(int);

    char* base = (char*)d_ws;
    float2* im     = (float2*)base;
    int*    perm   = (int*)(base + im_bytes);
    int*    hist   = (int*)(base + im_bytes + perm_bytes);
    int*    cursor = hist + ntiles;

    const int nblkN  = (N + 255) / 256;
    const int nblkIm = (HW / 4 + 255) / 256;
    const int swzIm  = (nblkIm % NXCD) == 0 && (HW / 4) % 256 == 0;
    const int swzIt  = (nblkN % NXCD) == 0 && (N % 256) == 0;

    const bool sortOK = ws_size >= im_bytes + perm_bytes + aux_bytes;
    // cooperative gate: exact grid tiling + 8-divisible for banding +
    // co-resident grid (<=2048 blocks of 256 is far below capacity at 4/CU)
    const bool coopOK = sortOK && (N % 256 == 0) && (nblkN % NXCD) == 0 &&
                        ((HW / 4) % nblkN) == 0 && nblkN <= 2048;

    if (coopOK) {
        int Hh = H, Ww = W, Nn = N, HWw = HW;
        void* dPv = (void*)dP; void* imv = (void*)im; void* permv = (void*)perm;
        void* histv = (void*)hist; void* curv = (void*)cursor;
        void* indsv = (void*)inds; void* nitv = (void*)niter_p; void* outv = (void*)out;
        void* args[] = { &dPv, &imv, &permv, &histv, &curv, &indsv, &nitv, &outv,
                         &Hh, &Ww, &Nn, &HWw };
        hipError_t e = hipLaunchCooperativeKernel(
            (const void*)fused_kernel, dim3(nblkN), dim3(256), args, 0, stream);
        if (e == hipSuccess) return;
        (void)hipGetLastError();   // clear and fall through to multi-launch
    }

    if (sortOK) {
        interleave_kernel<<<nblkIm, 256, 0, stream>>>(dP, im, HW, s0, s1, swzIm);
        zero_kernel<<<(ntiles + 255) / 256, 256, 0, stream>>>(hist, ntiles);
        hist_kernel<<<nblkN, 256, 0, stream>>>(inds, hist, N, H, W, tiles_x);
        scan_kernel<<<1, 1024, 0, stream>>>(hist, cursor, ntiles);
        scatter_kernel<<<nblkN, 256, 0, stream>>>(inds, cursor, perm, N, H, W, tiles_x);
        iterate1_kernel<2><<<nblkN, 256, 0, stream>>>(
            im, dP, perm, inds, niter_p, out, H, W, N, swzIt);
    } else if (ws_size >= im_bytes) {
        interleave_kernel<<<nblkIm, 256, 0, stream>>>(dP, im, HW, s0, s1, swzIm);
        iterate1_kernel<1><<<nblkN, 256, 0, stream>>>(
            im, dP, nullptr, inds, niter_p, out, H, W, N, 0);
    } else {
        iterate1_kernel<0><<<nblkN, 256, 0, stream>>>(
            nullptr, dP, nullptr, inds, niter_p, out, H, W, N, 0);
    }
}

// Round 15
// 218.136 us; speedup vs baseline: 3.0545x; 3.0545x over previous
//
#include <hip/hip_runtime.h>

#define TILE_SHIFT 5   // 32x32-px tiles
#define NXCD 8

// Journal:
// R12: quad LDS staging REGRESSED (117.8 vs 105us) - ds_read ~120cy not << L2,
//      63KB LDS halved occupancy. LDS staging is a dead end here.
// R13: fused cooperative kernel REGRESSED 2.6x (600us): grid.sync on 8 XCDs
//      = device-scope L2 writeback/invalidate per phase (WRITE 86MB, VALU 5.8%)
//      + cooperative dispatch breaks blockIdx->XCD banding. Pre-pass stays
//      multi-launch; never grid.sync between L2-locality-dependent phases.
// R14: halve gather count: (v00,v10) and (v01,v11) are adjacent float2 pairs
//      -> one 16B load each (ext_vector aligned(8)); MLP-latency model says
//      time ~ requests when outstanding-limited.

typedef float f4a8 __attribute__((ext_vector_type(4), aligned(8)));

__device__ __forceinline__ int point_tile_rm(const int* inds, int n, int N,
                                             int H, int W, int tiles_x)
{
    int y = inds[n];
    int x = inds[N + n];
    int ty = min(max(y, 0), H - 1) >> TILE_SHIFT;
    int tx = min(max(x, 0), W - 1) >> TILE_SHIFT;
    return ty * tiles_x + tx;
}

// ---------------------------------------------------------------------------
// planar (2,H,W) f32 -> interleaved pre-scaled float2 image (R11-verified).
// ---------------------------------------------------------------------------
__global__ __launch_bounds__(256) void interleave_kernel(
    const float* __restrict__ dP, float2* __restrict__ im,
    int HW, float s0, float s1, int swz_on)
{
    int bid = blockIdx.x;
    if (swz_on) {
        int cpx = gridDim.x >> 3;
        bid = (bid & (NXCD - 1)) * cpx + (bid >> 3);
    }
    int i = bid * blockDim.x + threadIdx.x;
    int nquad = HW >> 2;
    if (i >= nquad) return;
    const float4* p0 = reinterpret_cast<const float4*>(dP);
    const float4* p1 = reinterpret_cast<const float4*>(dP + HW);
    float4 a = p1[i];
    float4 b = p0[i];
    float4 lo, hi;
    lo.x = a.x * s0; lo.y = b.x * s1; lo.z = a.y * s0; lo.w = b.y * s1;
    hi.x = a.z * s0; hi.y = b.z * s1; hi.z = a.w * s0; hi.w = b.w * s1;
    float4* outv = reinterpret_cast<float4*>(im);
    outv[2 * i]     = lo;
    outv[2 * i + 1] = hi;
}

__global__ __launch_bounds__(256) void zero_kernel(int* __restrict__ p, int n)
{
    int i = blockIdx.x * blockDim.x + threadIdx.x;
    if (i < n) p[i] = 0;
}

__global__ __launch_bounds__(256) void hist_kernel(
    const int* __restrict__ inds, int* __restrict__ hist,
    int N, int H, int W, int tiles_x)
{
    int n = blockIdx.x * blockDim.x + threadIdx.x;
    if (n >= N) return;
    atomicAdd(&hist[point_tile_rm(inds, n, N, H, W, tiles_x)], 1);
}

__global__ __launch_bounds__(1024) void scan_kernel(
    const int* __restrict__ hist, int* __restrict__ cursor, int ntiles)
{
    __shared__ int partial[1024];
    const int tid = threadIdx.x;
    const int items = (ntiles + 1023) >> 10;
    const int base = tid * items;
    int sum = 0;
    for (int i = 0; i < items; ++i) {
        int idx = base + i;
        if (idx < ntiles) sum += hist[idx];
    }
    partial[tid] = sum;
    __syncthreads();
    for (int off = 1; off < 1024; off <<= 1) {
        int v = (tid >= off) ? partial[tid - off] : 0;
        __syncthreads();
        partial[tid] += v;
        __syncthreads();
    }
    int excl = (tid == 0) ? 0 : partial[tid - 1];
    for (int i = 0; i < items; ++i) {
        int idx = base + i;
        if (idx < ntiles) {
            int h = hist[idx];
            cursor[idx] = excl;
            excl += h;
        }
    }
}

__global__ __launch_bounds__(256) void scatter_kernel(
    const int* __restrict__ inds, int* __restrict__ cursor,
    int* __restrict__ perm, int N, int H, int W, int tiles_x)
{
    int n = blockIdx.x * blockDim.x + threadIdx.x;
    if (n >= N) return;
    int slot = atomicAdd(&cursor[point_tile_rm(inds, n, N, H, W, tiles_x)], 1);
    perm[slot] = n;
}

// ---------------------------------------------------------------------------
// Trajectory iteration, 1 pt/thread, XCD-banded, tile-sorted.  Row-pair
// gathers: (v00,v10) one 16B load, (v01,v11) one 16B load.  When x1c==x0c
// (left/right clamp) the needed corner is the LO half; the unused half is
// masked by bx*/by* exactly as before -> bitwise-identical output to R11.
//   MODE 2: image + perm.  MODE 1: image, unsorted.  MODE 0: planar dP.
// ---------------------------------------------------------------------------
template <int MODE>
__global__ __launch_bounds__(256) void iterate1_kernel(
    const float2* __restrict__ im, const float* __restrict__ dP,
    const int* __restrict__ perm,
    const int* __restrict__ inds, const int* __restrict__ niter_p,
    float* __restrict__ out, int H, int W, int N, int swz_on)
{
#pragma clang fp contract(off)
    int bid = blockIdx.x;
    if (swz_on) {
        int cpx = gridDim.x >> 3;
        bid = (bid & (NXCD - 1)) * cpx + (bid >> 3);
    }
    const int t = bid * blockDim.x + threadIdx.x;
    if (t >= N) return;
    const int niter = niter_p[0];
    const float sH = (float)(H - 1);
    const float sW = (float)(W - 1);
    const float s0 = 2.0f / sH;
    const float s1 = 2.0f / sW;
    const int HW = H * W;
    const float Wf = (float)W, Hf = (float)H;

    const int pid = (MODE == 2) ? perm[t] : t;

    float px = ((float)inds[N + pid] / sH) * 2.0f - 1.0f;
    float py = ((float)inds[pid]     / sW) * 2.0f - 1.0f;

    for (int it = 0; it < niter; ++it) {
        float x = ((px + 1.0f) * Wf - 1.0f) * 0.5f;
        float y = ((py + 1.0f) * Hf - 1.0f) * 0.5f;
        float x0f = floorf(x), y0f = floorf(y);
        float wx1 = x - x0f,  wy1 = y - y0f;
        float wx0 = 1.0f - wx1, wy0 = 1.0f - wy1;
        int x0 = (int)x0f, y0 = (int)y0f;
        int x1 = x0 + 1,   y1 = y0 + 1;

        int x0c = min(max(x0, 0), W - 1);
        int x1c = min(max(x1, 0), W - 1);
        int y0c = min(max(y0, 0), H - 1);
        int y1c = min(max(y1, 0), H - 1);
        bool bx0 = (x0 >= 0) & (x0 < W);
        bool bx1 = (x1 >= 0) & (x1 < W);
        bool by0 = (y0 >= 0) & (y0 < H);
        bool by1 = (y1 >= 0) & (y1 < H);

        float2 v00, v10, v01, v11;
        if (MODE >= 1) {
            const bool two = x1c > x0c;                 // false only at clamp
            f4a8 ra = *reinterpret_cast<const f4a8*>(im + (size_t)y0c * W + x0c);
            f4a8 rb = *reinterpret_cast<const f4a8*>(im + (size_t)y1c * W + x0c);
            v00 = make_float2(ra.x, ra.y);
            v10 = two ? make_float2(ra.z, ra.w) : make_float2(ra.x, ra.y);
            v01 = make_float2(rb.x, rb.y);
            v11 = two ? make_float2(rb.z, rb.w) : make_float2(rb.x, rb.y);
        } else {
            int i00 = y0c * W + x0c, i10 = y0c * W + x1c;
            int i01 = y1c * W + x0c, i11 = y1c * W + x1c;
            v00 = make_float2(dP[HW + i00] * s0, dP[i00] * s1);
            v10 = make_float2(dP[HW + i10] * s0, dP[i10] * s1);
            v01 = make_float2(dP[HW + i01] * s0, dP[i01] * s1);
            v11 = make_float2(dP[HW + i11] * s0, dP[i11] * s1);
        }
        const float2 zero = make_float2(0.0f, 0.0f);
        if (!(bx0 & by0)) v00 = zero;
        if (!(bx1 & by0)) v10 = zero;
        if (!(bx0 & by1)) v01 = zero;
        if (!(bx1 & by1)) v11 = zero;

        float w00 = wx0 * wy0, w10 = wx1 * wy0;
        float w01 = wx0 * wy1, w11 = wx1 * wy1;
        // left-to-right sum, exactly as the reference
        float dx = ((v00.x * w00 + v10.x * w10) + v01.x * w01) + v11.x * w11;
        float dy = ((v00.y * w00 + v10.y * w10) + v01.y * w01) + v11.y * w11;

        px = fminf(fmaxf(px + dx, -1.0f), 1.0f);
        py = fminf(fmaxf(py + dy, -1.0f), 1.0f);
    }

    out[pid]     = (py + 1.0f) * 0.5f * sW;
    out[N + pid] = (px + 1.0f) * 0.5f * sH;
}

extern "C" void kernel_launch(void* const* d_in, const int* in_sizes, int n_in,
                              void* d_out, int out_size, void* d_ws, size_t ws_size,
                              hipStream_t stream) {
    const float* dP      = (const float*)d_in[0];
    const int*   inds    = (const int*)d_in[1];
    const int*   niter_p = (const int*)d_in[2];
    float*       out     = (float*)d_out;

    const int HW = in_sizes[0] / 2;
    int W = 1;
    while ((long long)W * W < (long long)HW) W <<= 1;  // 4194304 -> 2048
    const int H = HW / W;
    const int N = in_sizes[1] / 2;

    const float s0 = 2.0f / (float)(H - 1);
    const float s1 = 2.0f / (float)(W - 1);

    const int tiles_x = ((W - 1) >> TILE_SHIFT) + 1;
    const int tiles_y = ((H - 1) >> TILE_SHIFT) + 1;
    const int ntiles  = tiles_x * tiles_y;

    const size_t im_bytes   = (size_t)HW * sizeof(float2);
    const size_t perm_bytes = (size_t)N * sizeof(int);
    const size_t aux_bytes  = (size_t)2 * ntiles * sizeof(int);

    char* base = (char*)d_ws;
    float2* im     = (float2*)base;
    int*    perm   = (int*)(base + im_bytes);
    int*    hist   = (int*)(base + im_bytes + perm_bytes);
    int*    cursor = hist + ntiles;

    const int nblkN  = (N + 255) / 256;
    const int nblkIm = (HW / 4 + 255) / 256;
    const int swzIm  = (nblkIm % NXCD) == 0 && (HW / 4) % 256 == 0;
    const int swzIt  = (nblkN % NXCD) == 0 && (N % 256) == 0;

    if (ws_size >= im_bytes + perm_bytes + aux_bytes) {
        interleave_kernel<<<nblkIm, 256, 0, stream>>>(dP, im, HW, s0, s1, swzIm);
        zero_kernel<<<(ntiles + 255) / 256, 256, 0, stream>>>(hist, ntiles);
        hist_kernel<<<nblkN, 256, 0, stream>>>(inds, hist, N, H, W, tiles_x);
        scan_kernel<<<1, 1024, 0, stream>>>(hist, cursor, ntiles);
        scatter_kernel<<<nblkN, 256, 0, stream>>>(inds, cursor, perm, N, H, W, tiles_x);
        iterate1_kernel<2><<<nblkN, 256, 0, stream>>>(
            im, dP, perm, inds, niter_p, out, H, W, N, swzIt);
    } else if (ws_size >= im_bytes + 16) {   // +16B: f4 tail-read slack
        interleave_kernel<<<nblkIm, 256, 0, stream>>>(dP, im, HW, s0, s1, swzIm);
        iterate1_kernel<1><<<nblkN, 256, 0, stream>>>(
            im, dP, nullptr, inds, niter_p, out, H, W, N, 0);
    } else {
        iterate1_kernel<0><<<nblkN, 256, 0, stream>>>(
            nullptr, dP, nullptr, inds, niter_p, out, H, W, N, 0);
    }
}